// Round 1
// baseline (412.221 us; speedup 1.0000x reference)
//
#include <hip/hip_runtime.h>

#define LT_W 0.5f
#define LIN_W 0.1f

__global__ __launch_bounds__(256) void apply_lt_lin_f4(
    const float4* __restrict__ x, float4* __restrict__ y, int n4) {
  int i = blockIdx.x * blockDim.x + threadIdx.x;
  if (i < n4) {
    float4 v = x[i];
    v.x = (v.x < LT_W) ? v.x * LIN_W : v.x;
    v.y = (v.y < LT_W) ? v.y * LIN_W : v.y;
    v.z = (v.z < LT_W) ? v.z * LIN_W : v.z;
    v.w = (v.w < LT_W) ? v.w * LIN_W : v.w;
    y[i] = v;
  }
}

extern "C" void kernel_launch(void* const* d_in, const int* in_sizes, int n_in,
                              void* d_out, int out_size, void* d_ws, size_t ws_size,
                              hipStream_t stream) {
  const float* x = (const float*)d_in[0];
  float* y = (float*)d_out;
  int n = in_sizes[0];          // 67108864, divisible by 4
  int n4 = n >> 2;              // 16777216 float4s
  int block = 256;
  int grid = (n4 + block - 1) / block;  // 65536 blocks
  apply_lt_lin_f4<<<grid, block, 0, stream>>>(
      (const float4*)x, (float4*)y, n4);
}